// Round 13
// baseline (1359.843 us; speedup 1.0000x reference)
//
#include <hip/hip_runtime.h>
#include <math.h>

// fp32 attention layer via split-bf16 (hi/lo) 3-term MFMA emulation.
// Interleaved storage: [row][(col/32)*64 + col%32 + plane*32].
// GEMM r13: r12 tiling (256x192, 8 waves 4Mx2N, 32x32x16 MFMA) with a
// FINE-INTERLEAVED tile body: 6 groups of {2-6 ds_reads | sched_barrier |
// 6 MFMAs on prev group's frags} -> each wave alternates LDS/matrix pipes
// at ~50-cyc quanta (compiler emits counted lgkm waits), overlapping the
// 2360-cyc LDS stream with the 2324-cyc MFMA stream that lockstep (r8/r12)
// serialized. One barrier/tile; drain-vmcnt boundary kept (FETCH guard).

typedef unsigned int u32;
typedef unsigned short u16;
typedef __attribute__((ext_vector_type(8))) short bf16x8;
typedef __attribute__((ext_vector_type(4))) float f32x4;
typedef __attribute__((ext_vector_type(16))) float f32x16;

#define MFMA(a, b, c) __builtin_amdgcn_mfma_f32_16x16x32_bf16((a), (b), (c), 0, 0, 0)
#define MFMA32(a, b, c) __builtin_amdgcn_mfma_f32_32x32x16_bf16((a), (b), (c), 0, 0, 0)

#define GLDS16(g, l) __builtin_amdgcn_global_load_lds( \
    (const __attribute__((address_space(1))) u32*)(g), \
    (__attribute__((address_space(3))) u32*)(l), 16, 0, 0)

__device__ __forceinline__ u16 f2bf(float f) {
  u32 u = __builtin_bit_cast(u32, f);
  return (u16)((u + 0x7fffu + ((u >> 16) & 1u)) >> 16);  // RNE
}
__device__ __forceinline__ float bf2f(u16 h) {
  u32 u = ((u32)h) << 16;
  return __builtin_bit_cast(float, u);
}
__device__ __forceinline__ void split2(float f, u16& h, u16& l) {
  h = f2bf(f);
  l = f2bf(f - bf2f(h));
}
__device__ __forceinline__ bf16x8 ld16(const u16* p) {
  return *reinterpret_cast<const bf16x8*>(p);
}

// ---------------------------------------------------------------- split ----
// fp32 [R][3072] -> interleaved hi/lo u16 [R][6144].
__global__ void split_kernel(const float* __restrict__ src, u16* __restrict__ dst,
                             long n) {
  long i = ((long)blockIdx.x * 256 + threadIdx.x) * 4;
  if (i >= n) return;
  const float4 v = *reinterpret_cast<const float4*>(src + i);
  const u32 i32 = (u32)i;
  const u32 row = i32 / 3072u;
  const u32 col = i32 - row * 3072u;
  const long base = (long)row * 6144 + (col >> 5) * 64 + (col & 31);
  ushort4 h, l;
  split2(v.x, h.x, l.x);
  split2(v.y, h.y, l.y);
  split2(v.z, h.z, l.z);
  split2(v.w, h.w, l.w);
  *reinterpret_cast<ushort4*>(dst + base) = h;
  *reinterpret_cast<ushort4*>(dst + base + 32) = l;
}

// --------------------------------------- 256x192 3-term GEMM, 32x32x16 ----
// C[M,N] = Ah*Bh^T + Ah*Bl^T + Al*Bh^T; A2[M][6144], B2[N][6144] interleaved.
// K=3072 -> NT=96 tiles of 32 (2 MFMA k-subs of 16). 8 waves (4M x 2N),
// wave tile 64x96: 2 m-frags x 3 n-frags of 32x32, acc 6 x f32x16 = 96
// VGPR. LDS: 2 dbuf x (A 256x64 + B 192x64) u16 = 112 KiB. Swizzle:
// slot = chunk ^ (row&7) ^ ((row>>3)&3) at glds source and ds_read.
// Tile body: stage 7 glds, then G0..G5 fine pipeline (reads lead MFMA by
// one group); vmcnt(0)+barrier at tile end only.
// MODE 0: write C interleaved u16 [M][2N].  MODE 1: fp32 C + bias[col].
template <int MODE>
__global__ __launch_bounds__(512, 2) void gemm32(
    const u16* __restrict__ A2, const u16* __restrict__ B2,
    int M, int N,
    u16* __restrict__ C2, float* __restrict__ Cf, const float* __restrict__ bias) {
  constexpr int NT = 96;
  __shared__ u16 ldsA[2][256 * 64];  // 64 KiB
  __shared__ u16 ldsB[2][192 * 64];  // 48 KiB
  const int tid = threadIdx.x;
  const int lane = tid & 63;
  const int w = tid >> 6;
  const int wm = w >> 1, wn = w & 1;  // 4M x 2N
  const int l31 = lane & 31;
  const int l5 = lane >> 5;

  const int mt = M >> 8;  // 16
  const int nwg = gridDim.x;
  const int bid = blockIdx.x;
  const int wg = (bid & 7) * (nwg >> 3) + (bid >> 3);  // XCD swizzle (nwg%8==0)
  const int bm = wg % mt, bn = wg / mt;

  const int srow = lane >> 3;  // 0..7
  // stage source chunk: slot (lane&7) holds chunk = (lane&7)^key(row),
  // key(row) = (row&7)^((row>>3)&3) = srow ^ (w&3)  (rows = j*64+w*8+srow)
  const int sgc = ((lane & 7) ^ srow ^ (w & 3)) * 8;

  auto stA = [&](int buf, int kt, int j) {
    const int r = j * 64 + w * 8 + srow;
    GLDS16(A2 + (long)(bm * 256 + r) * 6144 + kt * 64 + sgc,
           &ldsA[buf][(j * 64 + w * 8) * 64]);
  };
  auto stB = [&](int buf, int kt, int j) {
    const int r = j * 64 + w * 8 + srow;
    GLDS16(B2 + (long)(bn * 192 + r) * 6144 + kt * 64 + sgc,
           &ldsB[buf][(j * 64 + w * 8) * 64]);
  };

  f32x16 acc[2][3];
#pragma unroll
  for (int m = 0; m < 2; ++m)
#pragma unroll
    for (int n = 0; n < 3; ++n)
#pragma unroll
      for (int j = 0; j < 16; ++j) acc[m][n][j] = 0.f;

  // prologue: stage tile 0 into buf 0, drain
  stA(0, 0, 0); stA(0, 0, 1); stA(0, 0, 2); stA(0, 0, 3);
  stB(0, 0, 0); stB(0, 0, 1); stB(0, 0, 2);
  __syncthreads();

  const int aRow0 = wm * 64 + l31;
  const int bRow0 = wn * 96 + l31;
  // read key: frag row = base + (lane&31), bases multiples of 32 ->
  // key = (lane&7) ^ ((lane>>3)&3)
  const int rk = (lane & 7) ^ ((lane >> 3) & 3);

  // chunk(ksub, pl) = ksub*2 + l5 + pl*4 ; byte-slot = (chunk^rk)*8
#define CSLOT(KS, PL) ((((KS)*2 + l5 + (PL)*4) ^ rk) * 8)
#define SB() __builtin_amdgcn_sched_barrier(0)
  // 6 MFMAs: 3-term update of column NN with a-pair array A and b-pair BP
#define MG(A, BP, NN)                                                      \
  __builtin_amdgcn_s_setprio(1);                                           \
  _Pragma("unroll") for (int m = 0; m < 2; ++m) {                          \
    acc[m][NN] = MFMA32(A[m][0], (BP)[0], acc[m][NN]);                     \
    acc[m][NN] = MFMA32(A[m][0], (BP)[1], acc[m][NN]);                     \
    acc[m][NN] = MFMA32(A[m][1], (BP)[0], acc[m][NN]);                     \
  }                                                                        \
  __builtin_amdgcn_s_setprio(0);

  for (int t = 0; t < NT; ++t) {
    const int cur = t & 1;
    const int nxt = cur ^ 1;
    const u16* LA = ldsA[cur];
    const u16* LB = ldsB[cur];
    bf16x8 a0[2][2], a1[2][2], b0[3][2], b1[3][2];

    // stage full tile t+1 first (vmcnt-counted; drains at tile end)
    if (t + 1 < NT) {
      stA(nxt, t + 1, 0); stA(nxt, t + 1, 1);
      stA(nxt, t + 1, 2); stA(nxt, t + 1, 3);
      stB(nxt, t + 1, 0); stB(nxt, t + 1, 1); stB(nxt, t + 1, 2);
    }
    SB();
    // G0 reads: b0[0] + a0[0..1]  (6)
    b0[0][0] = ld16(&LB[bRow0 * 64 + CSLOT(0, 0)]);
    b0[0][1] = ld16(&LB[bRow0 * 64 + CSLOT(0, 1)]);
    a0[0][0] = ld16(&LA[aRow0 * 64 + CSLOT(0, 0)]);
    a0[0][1] = ld16(&LA[aRow0 * 64 + CSLOT(0, 1)]);
    a0[1][0] = ld16(&LA[(aRow0 + 32) * 64 + CSLOT(0, 0)]);
    a0[1][1] = ld16(&LA[(aRow0 + 32) * 64 + CSLOT(0, 1)]);
    SB();
    // G1 reads: b0[1]  (2)
    b0[1][0] = ld16(&LB[(bRow0 + 32) * 64 + CSLOT(0, 0)]);
    b0[1][1] = ld16(&LB[(bRow0 + 32) * 64 + CSLOT(0, 1)]);
    SB();
    MG(a0, b0[0], 0);  // ksub0, n=0
    SB();
    // G2 reads: b0[2]
    b0[2][0] = ld16(&LB[(bRow0 + 64) * 64 + CSLOT(0, 0)]);
    b0[2][1] = ld16(&LB[(bRow0 + 64) * 64 + CSLOT(0, 1)]);
    SB();
    MG(a0, b0[1], 1);  // ksub0, n=1
    SB();
    // G3 reads: b1[0] + a1[0..1]  (6)
    b1[0][0] = ld16(&LB[bRow0 * 64 + CSLOT(1, 0)]);
    b1[0][1] = ld16(&LB[bRow0 * 64 + CSLOT(1, 1)]);
    a1[0][0] = ld16(&LA[aRow0 * 64 + CSLOT(1, 0)]);
    a1[0][1] = ld16(&LA[aRow0 * 64 + CSLOT(1, 1)]);
    a1[1][0] = ld16(&LA[(aRow0 + 32) * 64 + CSLOT(1, 0)]);
    a1[1][1] = ld16(&LA[(aRow0 + 32) * 64 + CSLOT(1, 1)]);
    SB();
    MG(a0, b0[2], 2);  // ksub0, n=2
    SB();
    // G4 reads: b1[1]
    b1[1][0] = ld16(&LB[(bRow0 + 32) * 64 + CSLOT(1, 0)]);
    b1[1][1] = ld16(&LB[(bRow0 + 32) * 64 + CSLOT(1, 1)]);
    SB();
    MG(a1, b1[0], 0);  // ksub1, n=0
    SB();
    // G5 reads: b1[2]
    b1[2][0] = ld16(&LB[(bRow0 + 64) * 64 + CSLOT(1, 0)]);
    b1[2][1] = ld16(&LB[(bRow0 + 64) * 64 + CSLOT(1, 1)]);
    SB();
    MG(a1, b1[1], 1);  // ksub1, n=1
    SB();
    MG(a1, b1[2], 2);  // ksub1, n=2
    asm volatile("s_waitcnt vmcnt(0)" ::: "memory");
    __builtin_amdgcn_s_barrier();
  }
#undef CSLOT
#undef SB
#undef MG

  // epilogue: C/D col=lane&31, row=(reg&3)+8*(reg>>2)+4*(lane>>5) (m101)
#pragma unroll
  for (int mf = 0; mf < 2; ++mf)
#pragma unroll
    for (int nf = 0; nf < 3; ++nf) {
      const int col = bn * 192 + wn * 96 + nf * 32 + l31;
#pragma unroll
      for (int reg = 0; reg < 16; ++reg) {
        const int rif = (reg & 3) + 8 * (reg >> 2) + 4 * l5;
        const long row = (long)bm * 256 + wm * 64 + mf * 32 + rif;
        const float v = acc[mf][nf][reg];
        if (MODE == 0) {
          const long idx = row * (2L * N) + (col >> 5) * 64 + (col & 31);
          u16 h, l;
          split2(v, h, l);
          C2[idx] = h;
          C2[idx + 32] = l;
        } else {
          Cf[row * N + col] = v + bias[col];
        }
      }
    }
}

// ---------------------------------------------------------------- pack K ---
// K records from interleaved QKV2; Kp format unchanged (attn-compatible).
__global__ void pack_k(const u16* __restrict__ QKV2, u16* __restrict__ Kp) {
  const int t = blockIdx.x * 256 + threadIdx.x;
  const int lane = t & 63;
  const int rec3 = t >> 6;
  const int c = rec3 % 3;
  const int kb = (rec3 / 3) & 127;
  const int hl = rec3 / 384;
  const int lr = lane & 15, lg = lane >> 4;
  const long src = ((long)((hl >> 5) * 2048 + kb * 16 + lr)) * 18432 +
                   (96 + (hl & 31) * 3 + c) * 64 + lg * 8;
  const long dst = ((long)rec3 * 2) * 512 + lane * 8;
  *reinterpret_cast<bf16x8*>(Kp + dst) = ld16(QKV2 + src);
  *reinterpret_cast<bf16x8*>(Kp + dst + 512) = ld16(QKV2 + src + 32);
}

// ---------------------------------------------------------------- pack V ---
__global__ __launch_bounds__(256) void pack_v(const u16* __restrict__ QKV2,
                                              u16* __restrict__ Vp) {
  __shared__ u16 sV[2][32 * 96];
  const int tid = threadIdx.x;
  const int hl = blockIdx.x >> 6;
  const int kq = blockIdx.x & 63;
  const long rowbase = ((long)((hl >> 5) * 2048 + kq * 32)) * 18432 +
                       (192 + (hl & 31) * 3) * 64;
#pragma unroll
  for (int i = 0; i < 3; ++i) {
    const int idx = i * 256 + tid;  // [pl][row(32)][cu(12)]
    const int pl = idx / 384;
    const int r2 = idx % 384;
    const int row = r2 / 12, cu = r2 % 12;
    const long src = rowbase + (long)row * 18432 + (cu >> 2) * 64 + (cu & 3) * 8 + pl * 32;
    *reinterpret_cast<bf16x8*>(&sV[pl][row * 96 + cu * 8]) = ld16(QKV2 + src);
  }
  __syncthreads();
#pragma unroll
  for (int i = 0; i < 3; ++i) {
    const int idx = i * 256 + tid;
    const int lane = idx & 63;
    const int rl = idx >> 6;
    const int n = rl >> 1, pl = rl & 1;
    const int lr = lane & 15, lg = lane >> 4;
    bf16x8 o;
#pragma unroll
    for (int e = 0; e < 8; ++e) o[e] = (short)sV[pl][(lg * 8 + e) * 96 + n * 16 + lr];
    const long dst = ((((long)hl * 6 + n) * 64 + kq) * 2 + pl) * 512 + lane * 8;
    *reinterpret_cast<bf16x8*>(Vp + dst) = o;
  }
}

// ------------------------------------------------------------- attention ---
__global__ __launch_bounds__(256, 2) void attn_kernel(
    const u16* __restrict__ QKV2,
    const u16* __restrict__ Kp, const u16* __restrict__ Vp,
    u16* __restrict__ AO2) {
  __shared__ u16 kv[2][24 * 512];
  __shared__ u16 pb[4][2][512];
  const int lane = threadIdx.x & 63;
  const int wv = threadIdx.x >> 6;
  const int lr = lane & 15, lg = lane >> 4;

  const int nwg = gridDim.x;
  const int bid = blockIdx.x;
  const int wg = (bid & 7) * (nwg >> 3) + (bid >> 3);
  const int hl = wg >> 5;
  const int qblk = wg & 31;
  const int b = hl >> 5;
  const int q0 = qblk * 64 + wv * 16;

  bf16x8 qh[3], ql[3];
  {
    const long qofs =
        ((long)(b * 2048 + q0 + lr)) * 18432 + ((hl & 31) * 3) * 64 + lg * 8;
#pragma unroll
    for (int c = 0; c < 3; ++c) {
      qh[c] = ld16(QKV2 + qofs + c * 64);
      ql[c] = ld16(QKV2 + qofs + c * 64 + 32);
    }
  }

  f32x4 o_acc[6];
#pragma unroll
  for (int n = 0; n < 6; ++n)
#pragma unroll
    for (int j = 0; j < 4; ++j) o_acc[n][j] = 0.f;
  float lsum[4] = {0.f, 0.f, 0.f, 0.f};

  const float scale = 0.10206207261596577f;  // 96^-0.5
  u16* pbh = pb[wv][0];
  u16* pbl = pb[wv][1];

  auto stage = [&](int nb, int it) {
    const long kbase = ((long)hl * 768 + (long)it * 12) * 512;
    const long vbase = ((long)hl * 768 + (long)it * 2) * 512;
#pragma unroll
    for (int j = 0; j < 6; ++j) {
      const int r = wv * 6 + j;
      const u16* src;
      if (r < 12) {
        const int tt = r / 6, rc = r % 6;
        src = Kp + kbase + ((long)(tt * 6 + rc)) * 512 + lane * 8;
      } else {
        const int r2 = r - 12;
        src = Vp + vbase + ((long)((r2 >> 1) * 128 + (r2 & 1))) * 512 + lane * 8;
      }
      GLDS16(src, &kv[nb][r * 512]);
    }
  };

  stage(0, 0);
  __syncthreads();

  for (int it = 0; it < 64; ++it) {
    const int nb = it & 1;
    if (it < 63) stage(nb ^ 1, it + 1);
    const u16* L = kv[nb];

    f32x4 s0, s1;
#pragma unroll
    for (int j = 0; j < 4; ++j) { s0[j] = 0.f; s1[j] = 0.f; }
#pragma unroll
    for (int c = 0; c < 3; ++c) {
      const bf16x8 kh0 = ld16(L + (c * 2 + 0) * 512 + lane * 8);
      const bf16x8 kl0 = ld16(L + (c * 2 + 1) * 512 + lane * 8);
      const bf16x8 kh1 = ld16(L + (6 + c * 2 + 0) * 512 + lane * 8);
      const bf16x8 kl1 = ld16(L + (6 + c * 2 + 1) * 512 + lane * 8);
      s0 = MFMA(qh[c], kh0, s0);
      s1 = MFMA(qh[c], kh1, s1);
      s0 = MFMA(qh[c], kl0, s0);
      s1 = MFMA(qh[c], kl1, s1);
      s0 = MFMA(ql[c], kh0, s0);
      s1 = MFMA(ql[c], kh1, s1);
    }

#pragma unroll
    for (int j = 0; j < 4; ++j) {
      const float p0 = __expf(fmaf(s0[j], scale, -12.f));
      const float p1 = __expf(fmaf(s1[j], scale, -12.f));
      lsum[j] += p0 + p1;
      const int r = lg * 4 + j;
      const int key = j ^ lg;
      u16 h, l;
      split2(p0, h, l);
      const int a0 = r * 32 + ((((lr >> 3) ^ key) & 3) << 3) + (lr & 7);
      pbh[a0] = h;
      pbl[a0] = l;
      split2(p1, h, l);
      const int a1 = r * 32 + ((((2 + (lr >> 3)) ^ key) & 3) << 3) + (lr & 7);
      pbh[a1] = h;
      pbl[a1] = l;
    }
    const int rkey = (lr & 3) ^ (lr >> 2);
    const int ra = lr * 32 + (((lg ^ rkey) & 3) << 3);
    const bf16x8 pah = ld16(&pbh[ra]);
    const bf16x8 pal = ld16(&pbl[ra]);

#pragma unroll
    for (int n = 0; n < 6; ++n) {
      const bf16x8 vh = ld16(L + (12 + n * 2 + 0) * 512 + lane * 8);
      const bf16x8 vl = ld16(L + (12 + n * 2 + 1) * 512 + lane * 8);
      o_acc[n] = MFMA(pah, vh, o_acc[n]);
      o_acc[n] = MFMA(pah, vl, o_acc[n]);
      o_acc[n] = MFMA(pal, vh, o_acc[n]);
    }
    __syncthreads();
  }

  float inv[4];
#pragma unroll
  for (int j = 0; j < 4; ++j) {
    float rs = lsum[j];
#pragma unroll
    for (int mk = 1; mk < 16; mk <<= 1) rs += __shfl_xor(rs, mk);
    inv[j] = 1.f / rs;
  }
#pragma unroll
  for (int n = 0; n < 6; ++n)
#pragma unroll
    for (int j = 0; j < 4; ++j) {
      const long row = (long)(b * 2048 + q0 + lg * 4 + j);
      const long idx =
          row * 6144 + ((hl & 31) * 3 + (n >> 1)) * 64 + (n & 1) * 16 + lr;
      u16 h, l;
      split2(o_acc[n][j] * inv[j], h, l);
      AO2[idx] = h;
      AO2[idx + 32] = l;
    }
}

// ---------------------------------------------------------------- launch ---
extern "C" void kernel_launch(void* const* d_in, const int* in_sizes, int n_in,
                              void* d_out, int out_size, void* d_ws, size_t ws_size,
                              hipStream_t stream) {
  const float* x = (const float*)d_in[0];     // [4096][3072]
  const float* wqkv = (const float*)d_in[1];  // [9216][3072]
  const float* wo = (const float*)d_in[2];    // [3072][3072]
  const float* bo = (const float*)d_in[3];    // [3072]
  float* out = (float*)d_out;                 // [4096][3072]
  char* ws = (char*)d_ws;

  const size_t E_X = (size_t)4096 * 3072;
  const size_t E_WQ = (size_t)9216 * 3072;
  const size_t E_QKV = (size_t)4096 * 9216;
  const size_t E_WO = (size_t)3072 * 3072;

  // layout (bytes): X2[4E_X] | W2[4E_WQ] | QKV2[4E_QKV] | VP[4E_X]
  u16* X2 = (u16*)ws;
  char* W0 = ws + 4 * E_X;
  u16* W2 = (u16*)W0;
  char* Q0 = W0 + 4 * E_WQ;
  u16* QKV2 = (u16*)Q0;
  char* V0 = Q0 + 4 * E_QKV;
  u16* VP = (u16*)V0;
  u16* KP = (u16*)ws;              // reuses X2 region after GEMM1 (exact fit)
  u16* AO2 = (u16*)W0;             // reuses W2 region after GEMM1
  u16* WO2 = (u16*)(W0 + 4 * E_X);

  const size_t need = 4 * (E_X + E_WQ + E_QKV + E_X);
  if (ws_size < need) return;

  split_kernel<<<12288, 256, 0, stream>>>(x, X2, (long)E_X);
  split_kernel<<<27648, 256, 0, stream>>>(wqkv, W2, (long)E_WQ);
  gemm32<0><<<768, 512, 0, stream>>>(X2, W2, 4096, 9216, QKV2, nullptr, nullptr);
  pack_k<<<6144, 256, 0, stream>>>(QKV2, KP);
  pack_v<<<4096, 256, 0, stream>>>(QKV2, VP);
  split_kernel<<<9216, 256, 0, stream>>>(wo, WO2, (long)E_WO);
  attn_kernel<<<2048, 256, 0, stream>>>(QKV2, KP, VP, AO2);
  gemm32<1><<<256, 512, 0, stream>>>(AO2, WO2, 4096, 3072, nullptr, out, bo);
}

// Round 14
// 1318.278 us; speedup vs baseline: 1.0315x; 1.0315x over previous
//
#include <hip/hip_runtime.h>
#include <math.h>

// fp32 attention layer via split-bf16 (hi/lo) 3-term MFMA emulation.
// Interleaved storage: [row][(col/32)*64 + col%32 + plane*32].
// GEMM r14: r12's lockstep 2-phase body, resized to 128x192 tile / 256
// threads (4 waves 2Mx2N, wave 64x96) / 80 KB LDS -> TWO blocks per CU.
// The overlap every intra-block schedule failed to get (r5-r13) comes
// from inter-block concurrency (m114): while one block drains at its
// barrier, the other block's waves issue MFMA. Same reads/MFMA ratio,
// same swizzle, same sync; only the barrier-domain split changes.

typedef unsigned int u32;
typedef unsigned short u16;
typedef __attribute__((ext_vector_type(8))) short bf16x8;
typedef __attribute__((ext_vector_type(4))) float f32x4;
typedef __attribute__((ext_vector_type(16))) float f32x16;

#define MFMA(a, b, c) __builtin_amdgcn_mfma_f32_16x16x32_bf16((a), (b), (c), 0, 0, 0)
#define MFMA32(a, b, c) __builtin_amdgcn_mfma_f32_32x32x16_bf16((a), (b), (c), 0, 0, 0)

#define GLDS16(g, l) __builtin_amdgcn_global_load_lds( \
    (const __attribute__((address_space(1))) u32*)(g), \
    (__attribute__((address_space(3))) u32*)(l), 16, 0, 0)

__device__ __forceinline__ u16 f2bf(float f) {
  u32 u = __builtin_bit_cast(u32, f);
  return (u16)((u + 0x7fffu + ((u >> 16) & 1u)) >> 16);  // RNE
}
__device__ __forceinline__ float bf2f(u16 h) {
  u32 u = ((u32)h) << 16;
  return __builtin_bit_cast(float, u);
}
__device__ __forceinline__ void split2(float f, u16& h, u16& l) {
  h = f2bf(f);
  l = f2bf(f - bf2f(h));
}
__device__ __forceinline__ bf16x8 ld16(const u16* p) {
  return *reinterpret_cast<const bf16x8*>(p);
}

// ---------------------------------------------------------------- split ----
// fp32 [R][3072] -> interleaved hi/lo u16 [R][6144].
__global__ void split_kernel(const float* __restrict__ src, u16* __restrict__ dst,
                             long n) {
  long i = ((long)blockIdx.x * 256 + threadIdx.x) * 4;
  if (i >= n) return;
  const float4 v = *reinterpret_cast<const float4*>(src + i);
  const u32 i32 = (u32)i;
  const u32 row = i32 / 3072u;
  const u32 col = i32 - row * 3072u;
  const long base = (long)row * 6144 + (col >> 5) * 64 + (col & 31);
  ushort4 h, l;
  split2(v.x, h.x, l.x);
  split2(v.y, h.y, l.y);
  split2(v.z, h.z, l.z);
  split2(v.w, h.w, l.w);
  *reinterpret_cast<ushort4*>(dst + base) = h;
  *reinterpret_cast<ushort4*>(dst + base + 32) = l;
}

// --------------------------------------- 128x192 3-term GEMM, 32x32x16 ----
// C[M,N] = Ah*Bh^T + Ah*Bl^T + Al*Bh^T; A2[M][6144], B2[N][6144] interleaved.
// K=3072 -> NT=96 tiles of 32 (2 MFMA k-subs of 16). 4 waves (2M x 2N),
// wave tile 64x96: 2 m-frags x 3 n-frags of 32x32, acc 6 x f32x16 = 96
// VGPR. LDS: 2 dbuf x (A 128x64 + B 192x64) u16 = 80 KiB -> 2 blocks/CU.
// Swizzle: slot = chunk ^ (row&7) ^ ((row>>3)&3) at glds source + ds_read.
// Per tile (r12 lockstep):
//  ph0: rd ksub0 (10), stage t+1 (A4+B6) | bar,lgkm0,schedbar | 18 MFMA | bar
//  ph1: rd ksub1 (10) | bar,lgkm0,schedbar | 18 MFMA | vmcnt(0) | bar
// A/B frag: row=lane&31, k=(lane>>5)*8+e. C/D (m101): col=lane&31,
// row=(reg&3)+8*(reg>>2)+4*(lane>>5).
// MODE 0: write C interleaved u16 [M][2N].  MODE 1: fp32 C + bias[col].
template <int MODE>
__global__ __launch_bounds__(256, 2) void gemm32(
    const u16* __restrict__ A2, const u16* __restrict__ B2,
    int M, int N,
    u16* __restrict__ C2, float* __restrict__ Cf, const float* __restrict__ bias) {
  constexpr int NT = 96;
  __shared__ u16 ldsA[2][128 * 64];  // 32 KiB
  __shared__ u16 ldsB[2][192 * 64];  // 48 KiB
  const int tid = threadIdx.x;
  const int lane = tid & 63;
  const int w = tid >> 6;             // 0..3
  const int wm = w >> 1, wn = w & 1;  // 2M x 2N
  const int l31 = lane & 31;
  const int l5 = lane >> 5;

  const int mt = M >> 7;  // 128-row tiles
  const int nwg = gridDim.x;
  const int bid = blockIdx.x;
  const int wg = (bid & 7) * (nwg >> 3) + (bid >> 3);  // XCD swizzle (nwg%8==0)
  const int bm = wg % mt, bn = wg / mt;

  const int srow = lane >> 3;  // 0..7
  // stage rows = j*32 + w*8 + srow -> key(row) = (row&7)^((row>>3)&3)
  //            = srow ^ w  (j*4 ≡ 0 mod 4)
  const int sgc = ((lane & 7) ^ srow ^ w) * 8;

  auto stA = [&](int buf, int kt, int j) {
    const int r = j * 32 + w * 8 + srow;
    GLDS16(A2 + (long)(bm * 128 + r) * 6144 + kt * 64 + sgc,
           &ldsA[buf][(j * 32 + w * 8) * 64]);
  };
  auto stB = [&](int buf, int kt, int j) {
    const int r = j * 32 + w * 8 + srow;
    GLDS16(B2 + (long)(bn * 192 + r) * 6144 + kt * 64 + sgc,
           &ldsB[buf][(j * 32 + w * 8) * 64]);
  };

  f32x16 acc[2][3];
#pragma unroll
  for (int m = 0; m < 2; ++m)
#pragma unroll
    for (int n = 0; n < 3; ++n)
#pragma unroll
      for (int j = 0; j < 16; ++j) acc[m][n][j] = 0.f;

  // prologue: stage tile 0 into buf 0, drain
  stA(0, 0, 0); stA(0, 0, 1); stA(0, 0, 2); stA(0, 0, 3);
  stB(0, 0, 0); stB(0, 0, 1); stB(0, 0, 2);
  stB(0, 0, 3); stB(0, 0, 4); stB(0, 0, 5);
  __syncthreads();

  const int aRow0 = wm * 64 + l31;
  const int bRow0 = wn * 96 + l31;
  // read key: frag row = base(mult of 32) + (lane&31)
  const int rk = (lane & 7) ^ ((lane >> 3) & 3);

  // chunk(ksub, pl) = ksub*2 + l5 + pl*4 ; byte-slot = (chunk^rk)*8
#define CSLOT(KS, PL) ((((KS)*2 + l5 + (PL)*4) ^ rk) * 8)
#define RD_PH(KS)                                                          \
  _Pragma("unroll") for (int n = 0; n < 3; ++n) {                          \
    const int off = (bRow0 + n * 32) * 64;                                 \
    b[n][0] = ld16(&LB[off + CSLOT(KS, 0)]);                               \
    b[n][1] = ld16(&LB[off + CSLOT(KS, 1)]);                               \
  }                                                                        \
  _Pragma("unroll") for (int m = 0; m < 2; ++m) {                          \
    const int off = (aRow0 + m * 32) * 64;                                 \
    a[m][0] = ld16(&LA[off + CSLOT(KS, 0)]);                               \
    a[m][1] = ld16(&LA[off + CSLOT(KS, 1)]);                               \
  }
#define DO_MFMA3()                                                         \
  __builtin_amdgcn_s_setprio(1);                                           \
  _Pragma("unroll") for (int m = 0; m < 2; ++m)                            \
  _Pragma("unroll") for (int n = 0; n < 3; ++n) {                          \
    acc[m][n] = MFMA32(a[m][0], b[n][0], acc[m][n]);                       \
    acc[m][n] = MFMA32(a[m][0], b[n][1], acc[m][n]);                       \
    acc[m][n] = MFMA32(a[m][1], b[n][0], acc[m][n]);                       \
  }                                                                        \
  __builtin_amdgcn_s_setprio(0);
#define PH_SYNC()                                                          \
  __builtin_amdgcn_s_barrier();                                            \
  asm volatile("s_waitcnt lgkmcnt(0)" ::: "memory");                       \
  __builtin_amdgcn_sched_barrier(0);

  for (int t = 0; t < NT; ++t) {
    const int cur = t & 1;
    const int nxt = cur ^ 1;
    const u16* LA = ldsA[cur];
    const u16* LB = ldsB[cur];
    bf16x8 a[2][2], b[3][2];
    // ph0: ksub 0 reads; stage full tile t+1
    RD_PH(0);
    if (t + 1 < NT) {
      stA(nxt, t + 1, 0); stA(nxt, t + 1, 1);
      stA(nxt, t + 1, 2); stA(nxt, t + 1, 3);
      stB(nxt, t + 1, 0); stB(nxt, t + 1, 1); stB(nxt, t + 1, 2);
      stB(nxt, t + 1, 3); stB(nxt, t + 1, 4); stB(nxt, t + 1, 5);
    }
    PH_SYNC();
    DO_MFMA3();
    __builtin_amdgcn_s_barrier();
    // ph1: ksub 1
    RD_PH(1);
    PH_SYNC();
    DO_MFMA3();
    asm volatile("s_waitcnt vmcnt(0)" ::: "memory");
    __builtin_amdgcn_s_barrier();
  }
#undef CSLOT
#undef RD_PH
#undef DO_MFMA3
#undef PH_SYNC

  // epilogue: C/D col=lane&31, row=(reg&3)+8*(reg>>2)+4*(lane>>5) (m101)
#pragma unroll
  for (int mf = 0; mf < 2; ++mf)
#pragma unroll
    for (int nf = 0; nf < 3; ++nf) {
      const int col = bn * 192 + wn * 96 + nf * 32 + l31;
#pragma unroll
      for (int reg = 0; reg < 16; ++reg) {
        const int rif = (reg & 3) + 8 * (reg >> 2) + 4 * l5;
        const long row = (long)bm * 128 + wm * 64 + mf * 32 + rif;
        const float v = acc[mf][nf][reg];
        if (MODE == 0) {
          const long idx = row * (2L * N) + (col >> 5) * 64 + (col & 31);
          u16 h, l;
          split2(v, h, l);
          C2[idx] = h;
          C2[idx + 32] = l;
        } else {
          Cf[row * N + col] = v + bias[col];
        }
      }
    }
}

// ---------------------------------------------------------------- pack K ---
// K records from interleaved QKV2; Kp format unchanged (attn-compatible).
__global__ void pack_k(const u16* __restrict__ QKV2, u16* __restrict__ Kp) {
  const int t = blockIdx.x * 256 + threadIdx.x;
  const int lane = t & 63;
  const int rec3 = t >> 6;
  const int c = rec3 % 3;
  const int kb = (rec3 / 3) & 127;
  const int hl = rec3 / 384;
  const int lr = lane & 15, lg = lane >> 4;
  const long src = ((long)((hl >> 5) * 2048 + kb * 16 + lr)) * 18432 +
                   (96 + (hl & 31) * 3 + c) * 64 + lg * 8;
  const long dst = ((long)rec3 * 2) * 512 + lane * 8;
  *reinterpret_cast<bf16x8*>(Kp + dst) = ld16(QKV2 + src);
  *reinterpret_cast<bf16x8*>(Kp + dst + 512) = ld16(QKV2 + src + 32);
}

// ---------------------------------------------------------------- pack V ---
__global__ __launch_bounds__(256) void pack_v(const u16* __restrict__ QKV2,
                                              u16* __restrict__ Vp) {
  __shared__ u16 sV[2][32 * 96];
  const int tid = threadIdx.x;
  const int hl = blockIdx.x >> 6;
  const int kq = blockIdx.x & 63;
  const long rowbase = ((long)((hl >> 5) * 2048 + kq * 32)) * 18432 +
                       (192 + (hl & 31) * 3) * 64;
#pragma unroll
  for (int i = 0; i < 3; ++i) {
    const int idx = i * 256 + tid;  // [pl][row(32)][cu(12)]
    const int pl = idx / 384;
    const int r2 = idx % 384;
    const int row = r2 / 12, cu = r2 % 12;
    const long src = rowbase + (long)row * 18432 + (cu >> 2) * 64 + (cu & 3) * 8 + pl * 32;
    *reinterpret_cast<bf16x8*>(&sV[pl][row * 96 + cu * 8]) = ld16(QKV2 + src);
  }
  __syncthreads();
#pragma unroll
  for (int i = 0; i < 3; ++i) {
    const int idx = i * 256 + tid;
    const int lane = idx & 63;
    const int rl = idx >> 6;
    const int n = rl >> 1, pl = rl & 1;
    const int lr = lane & 15, lg = lane >> 4;
    bf16x8 o;
#pragma unroll
    for (int e = 0; e < 8; ++e) o[e] = (short)sV[pl][(lg * 8 + e) * 96 + n * 16 + lr];
    const long dst = ((((long)hl * 6 + n) * 64 + kq) * 2 + pl) * 512 + lane * 8;
    *reinterpret_cast<bf16x8*>(Vp + dst) = o;
  }
}

// ------------------------------------------------------------- attention ---
__global__ __launch_bounds__(256, 2) void attn_kernel(
    const u16* __restrict__ QKV2,
    const u16* __restrict__ Kp, const u16* __restrict__ Vp,
    u16* __restrict__ AO2) {
  __shared__ u16 kv[2][24 * 512];
  __shared__ u16 pb[4][2][512];
  const int lane = threadIdx.x & 63;
  const int wv = threadIdx.x >> 6;
  const int lr = lane & 15, lg = lane >> 4;

  const int nwg = gridDim.x;
  const int bid = blockIdx.x;
  const int wg = (bid & 7) * (nwg >> 3) + (bid >> 3);
  const int hl = wg >> 5;
  const int qblk = wg & 31;
  const int b = hl >> 5;
  const int q0 = qblk * 64 + wv * 16;

  bf16x8 qh[3], ql[3];
  {
    const long qofs =
        ((long)(b * 2048 + q0 + lr)) * 18432 + ((hl & 31) * 3) * 64 + lg * 8;
#pragma unroll
    for (int c = 0; c < 3; ++c) {
      qh[c] = ld16(QKV2 + qofs + c * 64);
      ql[c] = ld16(QKV2 + qofs + c * 64 + 32);
    }
  }

  f32x4 o_acc[6];
#pragma unroll
  for (int n = 0; n < 6; ++n)
#pragma unroll
    for (int j = 0; j < 4; ++j) o_acc[n][j] = 0.f;
  float lsum[4] = {0.f, 0.f, 0.f, 0.f};

  const float scale = 0.10206207261596577f;  // 96^-0.5
  u16* pbh = pb[wv][0];
  u16* pbl = pb[wv][1];

  auto stage = [&](int nb, int it) {
    const long kbase = ((long)hl * 768 + (long)it * 12) * 512;
    const long vbase = ((long)hl * 768 + (long)it * 2) * 512;
#pragma unroll
    for (int j = 0; j < 6; ++j) {
      const int r = wv * 6 + j;
      const u16* src;
      if (r < 12) {
        const int tt = r / 6, rc = r % 6;
        src = Kp + kbase + ((long)(tt * 6 + rc)) * 512 + lane * 8;
      } else {
        const int r2 = r - 12;
        src = Vp + vbase + ((long)((r2 >> 1) * 128 + (r2 & 1))) * 512 + lane * 8;
      }
      GLDS16(src, &kv[nb][r * 512]);
    }
  };

  stage(0, 0);
  __syncthreads();

  for (int it = 0; it < 64; ++it) {
    const int nb = it & 1;
    if (it < 63) stage(nb ^ 1, it + 1);
    const u16* L = kv[nb];

    f32x4 s0, s1;
#pragma unroll
    for (int j = 0; j < 4; ++j) { s0[j] = 0.f; s1[j] = 0.f; }
#pragma unroll
    for (int c = 0; c < 3; ++c) {
      const bf16x8 kh0 = ld16(L + (c * 2 + 0) * 512 + lane * 8);
      const bf16x8 kl0 = ld16(L + (c * 2 + 1) * 512 + lane * 8);
      const bf16x8 kh1 = ld16(L + (6 + c * 2 + 0) * 512 + lane * 8);
      const bf16x8 kl1 = ld16(L + (6 + c * 2 + 1) * 512 + lane * 8);
      s0 = MFMA(qh[c], kh0, s0);
      s1 = MFMA(qh[c], kh1, s1);
      s0 = MFMA(qh[c], kl0, s0);
      s1 = MFMA(qh[c], kl1, s1);
      s0 = MFMA(ql[c], kh0, s0);
      s1 = MFMA(ql[c], kh1, s1);
    }

#pragma unroll
    for (int j = 0; j < 4; ++j) {
      const float p0 = __expf(fmaf(s0[j], scale, -12.f));
      const float p1 = __expf(fmaf(s1[j], scale, -12.f));
      lsum[j] += p0 + p1;
      const int r = lg * 4 + j;
      const int key = j ^ lg;
      u16 h, l;
      split2(p0, h, l);
      const int a0 = r * 32 + ((((lr >> 3) ^ key) & 3) << 3) + (lr & 7);
      pbh[a0] = h;
      pbl[a0] = l;
      split2(p1, h, l);
      const int a1 = r * 32 + ((((2 + (lr >> 3)) ^ key) & 3) << 3) + (lr & 7);
      pbh[a1] = h;
      pbl[a1] = l;
    }
    const int rkey = (lr & 3) ^ (lr >> 2);
    const int ra = lr * 32 + (((lg ^ rkey) & 3) << 3);
    const bf16x8 pah = ld16(&pbh[ra]);
    const bf16x8 pal = ld16(&pbl[ra]);

#pragma unroll
    for (int n = 0; n < 6; ++n) {
      const bf16x8 vh = ld16(L + (12 + n * 2 + 0) * 512 + lane * 8);
      const bf16x8 vl = ld16(L + (12 + n * 2 + 1) * 512 + lane * 8);
      o_acc[n] = MFMA(pah, vh, o_acc[n]);
      o_acc[n] = MFMA(pah, vl, o_acc[n]);
      o_acc[n] = MFMA(pal, vh, o_acc[n]);
    }
    __syncthreads();
  }

  float inv[4];
#pragma unroll
  for (int j = 0; j < 4; ++j) {
    float rs = lsum[j];
#pragma unroll
    for (int mk = 1; mk < 16; mk <<= 1) rs += __shfl_xor(rs, mk);
    inv[j] = 1.f / rs;
  }
#pragma unroll
  for (int n = 0; n < 6; ++n)
#pragma unroll
    for (int j = 0; j < 4; ++j) {
      const long row = (long)(b * 2048 + q0 + lg * 4 + j);
      const long idx =
          row * 6144 + ((hl & 31) * 3 + (n >> 1)) * 64 + (n & 1) * 16 + lr;
      u16 h, l;
      split2(o_acc[n][j] * inv[j], h, l);
      AO2[idx] = h;
      AO2[idx + 32] = l;
    }
}

// ---------------------------------------------------------------- launch ---
extern "C" void kernel_launch(void* const* d_in, const int* in_sizes, int n_in,
                              void* d_out, int out_size, void* d_ws, size_t ws_size,
                              hipStream_t stream) {
  const float* x = (const float*)d_in[0];     // [4096][3072]
  const float* wqkv = (const float*)d_in[1];  // [9216][3072]
  const float* wo = (const float*)d_in[2];    // [3072][3072]
  const float* bo = (const float*)d_in[3];    // [3072]
  float* out = (float*)d_out;                 // [4096][3072]
  char* ws = (char*)d_ws;

  const size_t E_X = (size_t)4096 * 3072;
  const size_t E_WQ = (size_t)9216 * 3072;
  const size_t E_QKV = (size_t)4096 * 9216;
  const size_t E_WO = (size_t)3072 * 3072;

  // layout (bytes): X2[4E_X] | W2[4E_WQ] | QKV2[4E_QKV] | VP[4E_X]
  u16* X2 = (u16*)ws;
  char* W0 = ws + 4 * E_X;
  u16* W2 = (u16*)W0;
  char* Q0 = W0 + 4 * E_WQ;
  u16* QKV2 = (u16*)Q0;
  char* V0 = Q0 + 4 * E_QKV;
  u16* VP = (u16*)V0;
  u16* KP = (u16*)ws;              // reuses X2 region after GEMM1 (exact fit)
  u16* AO2 = (u16*)W0;             // reuses W2 region after GEMM1
  u16* WO2 = (u16*)(W0 + 4 * E_X);

  const size_t need = 4 * (E_X + E_WQ + E_QKV + E_X);
  if (ws_size < need) return;

  split_kernel<<<12288, 256, 0, stream>>>(x, X2, (long)E_X);
  split_kernel<<<27648, 256, 0, stream>>>(wqkv, W2, (long)E_WQ);
  gemm32<0><<<1536, 256, 0, stream>>>(X2, W2, 4096, 9216, QKV2, nullptr, nullptr);
  pack_k<<<6144, 256, 0, stream>>>(QKV2, KP);
  pack_v<<<4096, 256, 0, stream>>>(QKV2, VP);
  split_kernel<<<9216, 256, 0, stream>>>(wo, WO2, (long)E_WO);
  attn_kernel<<<2048, 256, 0, stream>>>(QKV2, KP, VP, AO2);
  gemm32<1><<<512, 256, 0, stream>>>(AO2, WO2, 4096, 3072, nullptr, out, bo);
}

// Round 15
// 1216.273 us; speedup vs baseline: 1.1180x; 1.0839x over previous
//
#include <hip/hip_runtime.h>
#include <math.h>

// fp32 attention layer via split-bf16 (hi/lo) 3-term MFMA emulation.
// Interleaved storage: [row][(col/32)*64 + col%32 + plane*32].
// GEMM (r14, best): 128x192 tile, 256 thr, 80KB LDS -> 2 blocks/CU
// (inter-block overlap, m114). attn r15: 32 q-rows/wave (2 frags) --
// K/V register loads shared across frags, halving LDS-read per q-row
// (attn was LDS-read-bound: 24 shared reads now feed 72 MFMAs).

typedef unsigned int u32;
typedef unsigned short u16;
typedef __attribute__((ext_vector_type(8))) short bf16x8;
typedef __attribute__((ext_vector_type(4))) float f32x4;
typedef __attribute__((ext_vector_type(16))) float f32x16;

#define MFMA(a, b, c) __builtin_amdgcn_mfma_f32_16x16x32_bf16((a), (b), (c), 0, 0, 0)
#define MFMA32(a, b, c) __builtin_amdgcn_mfma_f32_32x32x16_bf16((a), (b), (c), 0, 0, 0)

#define GLDS16(g, l) __builtin_amdgcn_global_load_lds( \
    (const __attribute__((address_space(1))) u32*)(g), \
    (__attribute__((address_space(3))) u32*)(l), 16, 0, 0)

__device__ __forceinline__ u16 f2bf(float f) {
  u32 u = __builtin_bit_cast(u32, f);
  return (u16)((u + 0x7fffu + ((u >> 16) & 1u)) >> 16);  // RNE
}
__device__ __forceinline__ float bf2f(u16 h) {
  u32 u = ((u32)h) << 16;
  return __builtin_bit_cast(float, u);
}
__device__ __forceinline__ void split2(float f, u16& h, u16& l) {
  h = f2bf(f);
  l = f2bf(f - bf2f(h));
}
__device__ __forceinline__ bf16x8 ld16(const u16* p) {
  return *reinterpret_cast<const bf16x8*>(p);
}

// ---------------------------------------------------------------- split ----
// fp32 [R][3072] -> interleaved hi/lo u16 [R][6144].
__global__ void split_kernel(const float* __restrict__ src, u16* __restrict__ dst,
                             long n) {
  long i = ((long)blockIdx.x * 256 + threadIdx.x) * 4;
  if (i >= n) return;
  const float4 v = *reinterpret_cast<const float4*>(src + i);
  const u32 i32 = (u32)i;
  const u32 row = i32 / 3072u;
  const u32 col = i32 - row * 3072u;
  const long base = (long)row * 6144 + (col >> 5) * 64 + (col & 31);
  ushort4 h, l;
  split2(v.x, h.x, l.x);
  split2(v.y, h.y, l.y);
  split2(v.z, h.z, l.z);
  split2(v.w, h.w, l.w);
  *reinterpret_cast<ushort4*>(dst + base) = h;
  *reinterpret_cast<ushort4*>(dst + base + 32) = l;
}

// --------------------------------------- 128x192 3-term GEMM, 32x32x16 ----
// C[M,N] = Ah*Bh^T + Ah*Bl^T + Al*Bh^T; A2[M][6144], B2[N][6144] interleaved.
// K=3072 -> NT=96 tiles of 32 (2 MFMA k-subs of 16). 4 waves (2M x 2N),
// wave tile 64x96: 2 m-frags x 3 n-frags of 32x32, acc 6 x f32x16 = 96
// VGPR. LDS: 2 dbuf x (A 128x64 + B 192x64) u16 = 80 KiB -> 2 blocks/CU.
// Swizzle: slot = chunk ^ (row&7) ^ ((row>>3)&3) at glds source + ds_read.
// MODE 0: write C interleaved u16 [M][2N].  MODE 1: fp32 C + bias[col].
template <int MODE>
__global__ __launch_bounds__(256, 2) void gemm32(
    const u16* __restrict__ A2, const u16* __restrict__ B2,
    int M, int N,
    u16* __restrict__ C2, float* __restrict__ Cf, const float* __restrict__ bias) {
  constexpr int NT = 96;
  __shared__ u16 ldsA[2][128 * 64];  // 32 KiB
  __shared__ u16 ldsB[2][192 * 64];  // 48 KiB
  const int tid = threadIdx.x;
  const int lane = tid & 63;
  const int w = tid >> 6;             // 0..3
  const int wm = w >> 1, wn = w & 1;  // 2M x 2N
  const int l31 = lane & 31;
  const int l5 = lane >> 5;

  const int mt = M >> 7;  // 128-row tiles
  const int nwg = gridDim.x;
  const int bid = blockIdx.x;
  const int wg = (bid & 7) * (nwg >> 3) + (bid >> 3);  // XCD swizzle (nwg%8==0)
  const int bm = wg % mt, bn = wg / mt;

  const int srow = lane >> 3;  // 0..7
  // stage rows = j*32 + w*8 + srow -> key(row) = (row&7)^((row>>3)&3)
  //            = srow ^ w  (j*4 ≡ 0 mod 4)
  const int sgc = ((lane & 7) ^ srow ^ w) * 8;

  auto stA = [&](int buf, int kt, int j) {
    const int r = j * 32 + w * 8 + srow;
    GLDS16(A2 + (long)(bm * 128 + r) * 6144 + kt * 64 + sgc,
           &ldsA[buf][(j * 32 + w * 8) * 64]);
  };
  auto stB = [&](int buf, int kt, int j) {
    const int r = j * 32 + w * 8 + srow;
    GLDS16(B2 + (long)(bn * 192 + r) * 6144 + kt * 64 + sgc,
           &ldsB[buf][(j * 32 + w * 8) * 64]);
  };

  f32x16 acc[2][3];
#pragma unroll
  for (int m = 0; m < 2; ++m)
#pragma unroll
    for (int n = 0; n < 3; ++n)
#pragma unroll
      for (int j = 0; j < 16; ++j) acc[m][n][j] = 0.f;

  // prologue: stage tile 0 into buf 0, drain
  stA(0, 0, 0); stA(0, 0, 1); stA(0, 0, 2); stA(0, 0, 3);
  stB(0, 0, 0); stB(0, 0, 1); stB(0, 0, 2);
  stB(0, 0, 3); stB(0, 0, 4); stB(0, 0, 5);
  __syncthreads();

  const int aRow0 = wm * 64 + l31;
  const int bRow0 = wn * 96 + l31;
  // read key: frag row = base(mult of 32) + (lane&31)
  const int rk = (lane & 7) ^ ((lane >> 3) & 3);

  // chunk(ksub, pl) = ksub*2 + l5 + pl*4 ; byte-slot = (chunk^rk)*8
#define CSLOT(KS, PL) ((((KS)*2 + l5 + (PL)*4) ^ rk) * 8)
#define RD_PH(KS)                                                          \
  _Pragma("unroll") for (int n = 0; n < 3; ++n) {                          \
    const int off = (bRow0 + n * 32) * 64;                                 \
    b[n][0] = ld16(&LB[off + CSLOT(KS, 0)]);                               \
    b[n][1] = ld16(&LB[off + CSLOT(KS, 1)]);                               \
  }                                                                        \
  _Pragma("unroll") for (int m = 0; m < 2; ++m) {                          \
    const int off = (aRow0 + m * 32) * 64;                                 \
    a[m][0] = ld16(&LA[off + CSLOT(KS, 0)]);                               \
    a[m][1] = ld16(&LA[off + CSLOT(KS, 1)]);                               \
  }
#define DO_MFMA3()                                                         \
  __builtin_amdgcn_s_setprio(1);                                           \
  _Pragma("unroll") for (int m = 0; m < 2; ++m)                            \
  _Pragma("unroll") for (int n = 0; n < 3; ++n) {                          \
    acc[m][n] = MFMA32(a[m][0], b[n][0], acc[m][n]);                       \
    acc[m][n] = MFMA32(a[m][0], b[n][1], acc[m][n]);                       \
    acc[m][n] = MFMA32(a[m][1], b[n][0], acc[m][n]);                       \
  }                                                                        \
  __builtin_amdgcn_s_setprio(0);
#define PH_SYNC()                                                          \
  __builtin_amdgcn_s_barrier();                                            \
  asm volatile("s_waitcnt lgkmcnt(0)" ::: "memory");                       \
  __builtin_amdgcn_sched_barrier(0);

  for (int t = 0; t < NT; ++t) {
    const int cur = t & 1;
    const int nxt = cur ^ 1;
    const u16* LA = ldsA[cur];
    const u16* LB = ldsB[cur];
    bf16x8 a[2][2], b[3][2];
    // ph0: ksub 0 reads; stage full tile t+1
    RD_PH(0);
    if (t + 1 < NT) {
      stA(nxt, t + 1, 0); stA(nxt, t + 1, 1);
      stA(nxt, t + 1, 2); stA(nxt, t + 1, 3);
      stB(nxt, t + 1, 0); stB(nxt, t + 1, 1); stB(nxt, t + 1, 2);
      stB(nxt, t + 1, 3); stB(nxt, t + 1, 4); stB(nxt, t + 1, 5);
    }
    PH_SYNC();
    DO_MFMA3();
    __builtin_amdgcn_s_barrier();
    // ph1: ksub 1
    RD_PH(1);
    PH_SYNC();
    DO_MFMA3();
    asm volatile("s_waitcnt vmcnt(0)" ::: "memory");
    __builtin_amdgcn_s_barrier();
  }
#undef CSLOT
#undef RD_PH
#undef DO_MFMA3
#undef PH_SYNC

  // epilogue: C/D col=lane&31, row=(reg&3)+8*(reg>>2)+4*(lane>>5) (m101)
#pragma unroll
  for (int mf = 0; mf < 2; ++mf)
#pragma unroll
    for (int nf = 0; nf < 3; ++nf) {
      const int col = bn * 192 + wn * 96 + nf * 32 + l31;
#pragma unroll
      for (int reg = 0; reg < 16; ++reg) {
        const int rif = (reg & 3) + 8 * (reg >> 2) + 4 * l5;
        const long row = (long)bm * 128 + wm * 64 + mf * 32 + rif;
        const float v = acc[mf][nf][reg];
        if (MODE == 0) {
          const long idx = row * (2L * N) + (col >> 5) * 64 + (col & 31);
          u16 h, l;
          split2(v, h, l);
          C2[idx] = h;
          C2[idx + 32] = l;
        } else {
          Cf[row * N + col] = v + bias[col];
        }
      }
    }
}

// ---------------------------------------------------------------- pack K ---
// K records from interleaved QKV2; Kp format unchanged (attn-compatible).
__global__ void pack_k(const u16* __restrict__ QKV2, u16* __restrict__ Kp) {
  const int t = blockIdx.x * 256 + threadIdx.x;
  const int lane = t & 63;
  const int rec3 = t >> 6;
  const int c = rec3 % 3;
  const int kb = (rec3 / 3) & 127;
  const int hl = rec3 / 384;
  const int lr = lane & 15, lg = lane >> 4;
  const long src = ((long)((hl >> 5) * 2048 + kb * 16 + lr)) * 18432 +
                   (96 + (hl & 31) * 3 + c) * 64 + lg * 8;
  const long dst = ((long)rec3 * 2) * 512 + lane * 8;
  *reinterpret_cast<bf16x8*>(Kp + dst) = ld16(QKV2 + src);
  *reinterpret_cast<bf16x8*>(Kp + dst + 512) = ld16(QKV2 + src + 32);
}

// ---------------------------------------------------------------- pack V ---
__global__ __launch_bounds__(256) void pack_v(const u16* __restrict__ QKV2,
                                              u16* __restrict__ Vp) {
  __shared__ u16 sV[2][32 * 96];
  const int tid = threadIdx.x;
  const int hl = blockIdx.x >> 6;
  const int kq = blockIdx.x & 63;
  const long rowbase = ((long)((hl >> 5) * 2048 + kq * 32)) * 18432 +
                       (192 + (hl & 31) * 3) * 64;
#pragma unroll
  for (int i = 0; i < 3; ++i) {
    const int idx = i * 256 + tid;  // [pl][row(32)][cu(12)]
    const int pl = idx / 384;
    const int r2 = idx % 384;
    const int row = r2 / 12, cu = r2 % 12;
    const long src = rowbase + (long)row * 18432 + (cu >> 2) * 64 + (cu & 3) * 8 + pl * 32;
    *reinterpret_cast<bf16x8*>(&sV[pl][row * 96 + cu * 8]) = ld16(QKV2 + src);
  }
  __syncthreads();
#pragma unroll
  for (int i = 0; i < 3; ++i) {
    const int idx = i * 256 + tid;
    const int lane = idx & 63;
    const int rl = idx >> 6;
    const int n = rl >> 1, pl = rl & 1;
    const int lr = lane & 15, lg = lane >> 4;
    bf16x8 o;
#pragma unroll
    for (int e = 0; e < 8; ++e) o[e] = (short)sV[pl][(lg * 8 + e) * 96 + n * 16 + lr];
    const long dst = ((((long)hl * 6 + n) * 64 + kq) * 2 + pl) * 512 + lane * 8;
    *reinterpret_cast<bf16x8*>(Vp + dst) = o;
  }
}

// ------------------------------------------------------------- attention ---
// r15: 32 q-rows per wave (2 x 16-row frags), block = 128 q-rows; K/V
// register loads hoisted + shared across frags (24 reads feed 72 MFMAs).
// Max-free softmax: p = exp(s*scale - 12); l-sum reduced once at end.
__global__ __launch_bounds__(256, 2) void attn_kernel(
    const u16* __restrict__ QKV2,
    const u16* __restrict__ Kp, const u16* __restrict__ Vp,
    u16* __restrict__ AO2) {
  __shared__ u16 kv[2][24 * 512];      // 48 KB
  __shared__ u16 pb[4][2][2][512];     // 16 KB: [wave][frag][plane]
  const int lane = threadIdx.x & 63;
  const int wv = threadIdx.x >> 6;
  const int lr = lane & 15, lg = lane >> 4;

  const int nwg = gridDim.x;
  const int bid = blockIdx.x;
  const int wg = (bid & 7) * (nwg >> 3) + (bid >> 3);  // XCD swizzle
  const int hl = wg >> 4;    // b*32 + head
  const int qblk = wg & 15;  // 16 q-blocks of 128 rows
  const int b = hl >> 5;
  const int q0 = qblk * 128 + wv * 32;

  bf16x8 qh[2][3], ql[2][3];
#pragma unroll
  for (int f = 0; f < 2; ++f) {
    const long qofs =
        ((long)(b * 2048 + q0 + f * 16 + lr)) * 18432 + ((hl & 31) * 3) * 64 + lg * 8;
#pragma unroll
    for (int c = 0; c < 3; ++c) {
      qh[f][c] = ld16(QKV2 + qofs + c * 64);
      ql[f][c] = ld16(QKV2 + qofs + c * 64 + 32);
    }
  }

  f32x4 o_acc[2][6];
#pragma unroll
  for (int f = 0; f < 2; ++f)
#pragma unroll
    for (int n = 0; n < 6; ++n)
#pragma unroll
      for (int j = 0; j < 4; ++j) o_acc[f][n][j] = 0.f;
  float lsum[2][4] = {{0.f, 0.f, 0.f, 0.f}, {0.f, 0.f, 0.f, 0.f}};

  const float scale = 0.10206207261596577f;  // 96^-0.5

  auto stage = [&](int nb, int it) {
    const long kbase = ((long)hl * 768 + (long)it * 12) * 512;
    const long vbase = ((long)hl * 768 + (long)it * 2) * 512;
#pragma unroll
    for (int j = 0; j < 6; ++j) {
      const int r = wv * 6 + j;
      const u16* src;
      if (r < 12) {
        const int tt = r / 6, rc = r % 6;
        src = Kp + kbase + ((long)(tt * 6 + rc)) * 512 + lane * 8;
      } else {
        const int r2 = r - 12;
        src = Vp + vbase + ((long)((r2 >> 1) * 128 + (r2 & 1))) * 512 + lane * 8;
      }
      GLDS16(src, &kv[nb][r * 512]);
    }
  };

  stage(0, 0);
  __syncthreads();

  for (int it = 0; it < 64; ++it) {
    const int nb = it & 1;
    if (it < 63) stage(nb ^ 1, it + 1);
    const u16* L = kv[nb];

    // hoisted K fragment loads (shared by both q-frags)
    bf16x8 kh0[3], kl0[3], kh1[3], kl1[3];
#pragma unroll
    for (int c = 0; c < 3; ++c) {
      kh0[c] = ld16(L + (c * 2 + 0) * 512 + lane * 8);
      kl0[c] = ld16(L + (c * 2 + 1) * 512 + lane * 8);
      kh1[c] = ld16(L + (6 + c * 2 + 0) * 512 + lane * 8);
      kl1[c] = ld16(L + (6 + c * 2 + 1) * 512 + lane * 8);
    }

    bf16x8 pah[2], pal[2];
#pragma unroll
    for (int f = 0; f < 2; ++f) {
      f32x4 s0, s1;
#pragma unroll
      for (int j = 0; j < 4; ++j) { s0[j] = 0.f; s1[j] = 0.f; }
#pragma unroll
      for (int c = 0; c < 3; ++c) {
        s0 = MFMA(qh[f][c], kh0[c], s0);
        s1 = MFMA(qh[f][c], kh1[c], s1);
        s0 = MFMA(qh[f][c], kl0[c], s0);
        s1 = MFMA(qh[f][c], kl1[c], s1);
        s0 = MFMA(ql[f][c], kh0[c], s0);
        s1 = MFMA(ql[f][c], kh1[c], s1);
      }
      u16* pbh = pb[wv][f][0];
      u16* pbl = pb[wv][f][1];
#pragma unroll
      for (int j = 0; j < 4; ++j) {
        const float p0 = __expf(fmaf(s0[j], scale, -12.f));
        const float p1 = __expf(fmaf(s1[j], scale, -12.f));
        lsum[f][j] += p0 + p1;
        const int r = lg * 4 + j;
        const int key = j ^ lg;
        u16 h, l;
        split2(p0, h, l);
        const int a0 = r * 32 + ((((lr >> 3) ^ key) & 3) << 3) + (lr & 7);
        pbh[a0] = h;
        pbl[a0] = l;
        split2(p1, h, l);
        const int a1 = r * 32 + ((((2 + (lr >> 3)) ^ key) & 3) << 3) + (lr & 7);
        pbh[a1] = h;
        pbl[a1] = l;
      }
      const int rkey = (lr & 3) ^ (lr >> 2);
      const int ra = lr * 32 + (((lg ^ rkey) & 3) << 3);
      pah[f] = ld16(&pbh[ra]);
      pal[f] = ld16(&pbl[ra]);
    }

#pragma unroll
    for (int n = 0; n < 6; ++n) {
      const bf16x8 vh = ld16(L + (12 + n * 2 + 0) * 512 + lane * 8);
      const bf16x8 vl = ld16(L + (12 + n * 2 + 1) * 512 + lane * 8);
#pragma unroll
      for (int f = 0; f < 2; ++f) {
        o_acc[f][n] = MFMA(pah[f], vh, o_acc[f][n]);
        o_acc[f][n] = MFMA(pah[f], vl, o_acc[f][n]);
        o_acc[f][n] = MFMA(pal[f], vh, o_acc[f][n]);
      }
    }
    __syncthreads();
  }

#pragma unroll
  for (int f = 0; f < 2; ++f) {
    float inv[4];
#pragma unroll
    for (int j = 0; j < 4; ++j) {
      float rs = lsum[f][j];
#pragma unroll
      for (int mk = 1; mk < 16; mk <<= 1) rs += __shfl_xor(rs, mk);
      inv[j] = 1.f / rs;
    }
#pragma unroll
    for (int n = 0; n < 6; ++n)
#pragma unroll
      for (int j = 0; j < 4; ++j) {
        const long row = (long)(b * 2048 + q0 + f * 16 + lg * 4 + j);
        const long idx =
            row * 6144 + ((hl & 31) * 3 + (n >> 1)) * 64 + (n & 1) * 16 + lr;
        u16 h, l;
        split2(o_acc[f][n][j] * inv[j], h, l);
        AO2[idx] = h;
        AO2[idx + 32] = l;
      }
  }
}

// ---------------------------------------------------------------- launch ---
extern "C" void kernel_launch(void* const* d_in, const int* in_sizes, int n_in,
                              void* d_out, int out_size, void* d_ws, size_t ws_size,
                              hipStream_t stream) {
  const float* x = (const float*)d_in[0];     // [4096][3072]
  const float* wqkv = (const float*)d_in[1];  // [9216][3072]
  const float* wo = (const float*)d_in[2];    // [3072][3072]
  const float* bo = (const float*)d_in[3];    // [3072]
  float* out = (float*)d_out;                 // [4096][3072]
  char* ws = (char*)d_ws;

  const size_t E_X = (size_t)4096 * 3072;
  const size_t E_WQ = (size_t)9216 * 3072;
  const size_t E_QKV = (size_t)4096 * 9216;
  const size_t E_WO = (size_t)3072 * 3072;

  // layout (bytes): X2[4E_X] | W2[4E_WQ] | QKV2[4E_QKV] | VP[4E_X]
  u16* X2 = (u16*)ws;
  char* W0 = ws + 4 * E_X;
  u16* W2 = (u16*)W0;
  char* Q0 = W0 + 4 * E_WQ;
  u16* QKV2 = (u16*)Q0;
  char* V0 = Q0 + 4 * E_QKV;
  u16* VP = (u16*)V0;
  u16* KP = (u16*)ws;              // reuses X2 region after GEMM1 (exact fit)
  u16* AO2 = (u16*)W0;             // reuses W2 region after GEMM1
  u16* WO2 = (u16*)(W0 + 4 * E_X);

  const size_t need = 4 * (E_X + E_WQ + E_QKV + E_X);
  if (ws_size < need) return;

  split_kernel<<<12288, 256, 0, stream>>>(x, X2, (long)E_X);
  split_kernel<<<27648, 256, 0, stream>>>(wqkv, W2, (long)E_WQ);
  gemm32<0><<<1536, 256, 0, stream>>>(X2, W2, 4096, 9216, QKV2, nullptr, nullptr);
  pack_k<<<6144, 256, 0, stream>>>(QKV2, KP);
  pack_v<<<4096, 256, 0, stream>>>(QKV2, VP);
  split_kernel<<<9216, 256, 0, stream>>>(wo, WO2, (long)E_WO);
  attn_kernel<<<1024, 256, 0, stream>>>(QKV2, KP, VP, AO2);
  gemm32<1><<<512, 256, 0, stream>>>(AO2, WO2, 4096, 3072, nullptr, out, bo);
}

// Round 16
// 1159.950 us; speedup vs baseline: 1.1723x; 1.0486x over previous
//
#include <hip/hip_runtime.h>
#include <math.h>

// fp32 attention layer via split-bf16 (hi/lo) 3-term MFMA emulation.
// Interleaved storage: [row][(col/32)*64 + col%32 + plane*32].
// r16: pack_k/pack_v FUSED into GEMM1's epilogue -- K/V-third blocks
// transpose their accumulator through LDS (reused staging buffer) and
// store directly in attn's packed record format; Q goes to a compact
// Q-only buffer. Saves the packs' 402 MB round-trip + 2 launches.
// GEMM core: r14 (128x192 tile, 2 blocks/CU). attn: r15 (32 q-rows/wave).

typedef unsigned int u32;
typedef unsigned short u16;
typedef __attribute__((ext_vector_type(8))) short bf16x8;
typedef __attribute__((ext_vector_type(4))) float f32x4;
typedef __attribute__((ext_vector_type(16))) float f32x16;

#define MFMA(a, b, c) __builtin_amdgcn_mfma_f32_16x16x32_bf16((a), (b), (c), 0, 0, 0)
#define MFMA32(a, b, c) __builtin_amdgcn_mfma_f32_32x32x16_bf16((a), (b), (c), 0, 0, 0)

#define GLDS16(g, l) __builtin_amdgcn_global_load_lds( \
    (const __attribute__((address_space(1))) u32*)(g), \
    (__attribute__((address_space(3))) u32*)(l), 16, 0, 0)

__device__ __forceinline__ u16 f2bf(float f) {
  u32 u = __builtin_bit_cast(u32, f);
  return (u16)((u + 0x7fffu + ((u >> 16) & 1u)) >> 16);  // RNE
}
__device__ __forceinline__ float bf2f(u16 h) {
  u32 u = ((u32)h) << 16;
  return __builtin_bit_cast(float, u);
}
__device__ __forceinline__ void split2(float f, u16& h, u16& l) {
  h = f2bf(f);
  l = f2bf(f - bf2f(h));
}
__device__ __forceinline__ bf16x8 ld16(const u16* p) {
  return *reinterpret_cast<const bf16x8*>(p);
}

// ---------------------------------------------------------------- split ----
// fp32 [R][3072] -> interleaved hi/lo u16 [R][6144].
__global__ void split_kernel(const float* __restrict__ src, u16* __restrict__ dst,
                             long n) {
  long i = ((long)blockIdx.x * 256 + threadIdx.x) * 4;
  if (i >= n) return;
  const float4 v = *reinterpret_cast<const float4*>(src + i);
  const u32 i32 = (u32)i;
  const u32 row = i32 / 3072u;
  const u32 col = i32 - row * 3072u;
  const long base = (long)row * 6144 + (col >> 5) * 64 + (col & 31);
  ushort4 h, l;
  split2(v.x, h.x, l.x);
  split2(v.y, h.y, l.y);
  split2(v.z, h.z, l.z);
  split2(v.w, h.w, l.w);
  *reinterpret_cast<ushort4*>(dst + base) = h;
  *reinterpret_cast<ushort4*>(dst + base + 32) = l;
}

// --------------------------------------- 128x192 3-term GEMM, 32x32x16 ----
// C = Ah*Bh^T + Ah*Bl^T + Al*Bh^T; A2[M][6144], B2[N][6144] interleaved.
// K=3072 -> NT=96 tiles of 32 (2 MFMA k-subs of 16). 4 waves (2M x 2N),
// wave tile 64x96, acc 6 x f32x16 = 96 VGPR. LDS 80 KiB -> 2 blocks/CU.
// MODE 1: fp32 C + bias (o_proj). MODE 2: QKV epilogue -- bn<16: compact
// Q2 [4096][6144]; bn 16..31: K packed records; bn>=32: V^T packed records
// (LDS-transpose via P[2][64][200], reusing staging LDS post-loop).
template <int MODE>
__global__ __launch_bounds__(256, 2) void gemm32(
    const u16* __restrict__ A2, const u16* __restrict__ B2,
    int M, int N, u16* __restrict__ C2, u16* __restrict__ Kp,
    u16* __restrict__ Vp, float* __restrict__ Cf, const float* __restrict__ bias) {
  constexpr int NT = 96;
  __shared__ u16 shm[2 * 128 * 64 + 2 * 192 * 64];  // 80 KiB
  u16* const uA = shm;                  // 2 x 128x64
  u16* const uB = shm + 2 * 128 * 64;   // 2 x 192x64
  const int tid = threadIdx.x;
  const int lane = tid & 63;
  const int w = tid >> 6;             // 0..3
  const int wm = w >> 1, wn = w & 1;  // 2M x 2N
  const int l31 = lane & 31;
  const int l5 = lane >> 5;

  const int mt = M >> 7;  // 128-row tiles
  const int nwg = gridDim.x;
  const int bid = blockIdx.x;
  const int wg = (bid & 7) * (nwg >> 3) + (bid >> 3);  // XCD swizzle (nwg%8==0)
  const int bm = wg % mt, bn = wg / mt;

  const int srow = lane >> 3;  // 0..7
  // stage rows = j*32 + w*8 + srow -> key(row) = (row&7)^((row>>3)&3) = srow^w
  const int sgc = ((lane & 7) ^ srow ^ w) * 8;

  auto stA = [&](int buf, int kt, int j) {
    const int r = j * 32 + w * 8 + srow;
    GLDS16(A2 + (long)(bm * 128 + r) * 6144 + kt * 64 + sgc,
           &uA[buf * 8192 + (j * 32 + w * 8) * 64]);
  };
  auto stB = [&](int buf, int kt, int j) {
    const int r = j * 32 + w * 8 + srow;
    GLDS16(B2 + (long)(bn * 192 + r) * 6144 + kt * 64 + sgc,
           &uB[buf * 12288 + (j * 32 + w * 8) * 64]);
  };

  f32x16 acc[2][3];
#pragma unroll
  for (int m = 0; m < 2; ++m)
#pragma unroll
    for (int n = 0; n < 3; ++n)
#pragma unroll
      for (int j = 0; j < 16; ++j) acc[m][n][j] = 0.f;

  // prologue
  stA(0, 0, 0); stA(0, 0, 1); stA(0, 0, 2); stA(0, 0, 3);
  stB(0, 0, 0); stB(0, 0, 1); stB(0, 0, 2);
  stB(0, 0, 3); stB(0, 0, 4); stB(0, 0, 5);
  __syncthreads();

  const int aRow0 = wm * 64 + l31;
  const int bRow0 = wn * 96 + l31;
  const int rk = (lane & 7) ^ ((lane >> 3) & 3);

#define CSLOT(KS, PL) ((((KS)*2 + l5 + (PL)*4) ^ rk) * 8)
#define RD_PH(KS)                                                          \
  _Pragma("unroll") for (int n = 0; n < 3; ++n) {                          \
    const int off = (bRow0 + n * 32) * 64;                                 \
    b[n][0] = ld16(&LB[off + CSLOT(KS, 0)]);                               \
    b[n][1] = ld16(&LB[off + CSLOT(KS, 1)]);                               \
  }                                                                        \
  _Pragma("unroll") for (int m = 0; m < 2; ++m) {                          \
    const int off = (aRow0 + m * 32) * 64;                                 \
    a[m][0] = ld16(&LA[off + CSLOT(KS, 0)]);                               \
    a[m][1] = ld16(&LA[off + CSLOT(KS, 1)]);                               \
  }
#define DO_MFMA3()                                                         \
  __builtin_amdgcn_s_setprio(1);                                           \
  _Pragma("unroll") for (int m = 0; m < 2; ++m)                            \
  _Pragma("unroll") for (int n = 0; n < 3; ++n) {                          \
    acc[m][n] = MFMA32(a[m][0], b[n][0], acc[m][n]);                       \
    acc[m][n] = MFMA32(a[m][0], b[n][1], acc[m][n]);                       \
    acc[m][n] = MFMA32(a[m][1], b[n][0], acc[m][n]);                       \
  }                                                                        \
  __builtin_amdgcn_s_setprio(0);
#define PH_SYNC()                                                          \
  __builtin_amdgcn_s_barrier();                                            \
  asm volatile("s_waitcnt lgkmcnt(0)" ::: "memory");                       \
  __builtin_amdgcn_sched_barrier(0);

  for (int t = 0; t < NT; ++t) {
    const int cur = t & 1;
    const int nxt = cur ^ 1;
    const u16* LA = &uA[cur * 8192];
    const u16* LB = &uB[cur * 12288];
    bf16x8 a[2][2], b[3][2];
    RD_PH(0);
    if (t + 1 < NT) {
      stA(nxt, t + 1, 0); stA(nxt, t + 1, 1);
      stA(nxt, t + 1, 2); stA(nxt, t + 1, 3);
      stB(nxt, t + 1, 0); stB(nxt, t + 1, 1); stB(nxt, t + 1, 2);
      stB(nxt, t + 1, 3); stB(nxt, t + 1, 4); stB(nxt, t + 1, 5);
    }
    PH_SYNC();
    DO_MFMA3();
    __builtin_amdgcn_s_barrier();
    RD_PH(1);
    PH_SYNC();
    DO_MFMA3();
    asm volatile("s_waitcnt vmcnt(0)" ::: "memory");
    __builtin_amdgcn_s_barrier();
  }
#undef CSLOT
#undef RD_PH
#undef DO_MFMA3
#undef PH_SYNC

  // epilogue. C/D: col=lane&31, row=(reg&3)+8*(reg>>2)+4*(lane>>5) (m101)
  if (MODE == 1 || (MODE == 2 && bn < 16)) {
#pragma unroll
    for (int mf = 0; mf < 2; ++mf)
#pragma unroll
      for (int nf = 0; nf < 3; ++nf) {
        const int col = bn * 192 + wn * 96 + nf * 32 + l31;
#pragma unroll
        for (int reg = 0; reg < 16; ++reg) {
          const int rif = (reg & 3) + 8 * (reg >> 2) + 4 * l5;
          const long row = (long)bm * 128 + wm * 64 + mf * 32 + rif;
          const float v = acc[mf][nf][reg];
          if (MODE == 1) {
            Cf[row * N + col] = v + bias[col];
          } else {  // compact Q2 [4096][6144]
            const long idx = row * 6144 + (col >> 5) * 64 + (col & 31);
            u16 h, l;
            split2(v, h, l);
            C2[idx] = h;
            C2[idx + 32] = l;
          }
        }
      }
  } else if (MODE == 2) {
    // K/V packed epilogue via LDS transpose. P[pl][64 s][200] (51.2 KB).
    const bool isV = (bn >= 32);
    const int hd0 = (bn - (isV ? 32 : 16)) * 2;  // first of 2 heads
    const int b = (bm * 128) >> 11;
    const int s_loc = (bm * 128) & 2047;
    u16* const P = shm;
    u16* const dst = isV ? Vp : Kp;
#pragma unroll
    for (int hf = 0; hf < 2; ++hf) {
      __syncthreads();
      if (wm == hf) {  // this wave owns rows hf*64 .. hf*64+63
#pragma unroll
        for (int mf = 0; mf < 2; ++mf)
#pragma unroll
          for (int nf = 0; nf < 3; ++nf)
#pragma unroll
            for (int reg = 0; reg < 16; ++reg) {
              const int rif = (reg & 3) + 8 * (reg >> 2) + 4 * l5;
              const int row_l = mf * 32 + rif;                // 0..63
              const int col_l = wn * 96 + nf * 32 + l31;      // 0..191
              u16 h, l;
              split2(acc[mf][nf][reg], h, l);
              P[row_l * 200 + col_l] = h;
              P[(64 + row_l) * 200 + col_l] = l;
            }
      }
      __syncthreads();
      const int lr = lane & 15, lg = lane >> 4;
      if (!isV) {
        // 48 records: ri = ((hh*3+c)*4+kbi)*2+pl; rec covers 16s x 32d.
#pragma unroll
        for (int i = 0; i < 12; ++i) {
          const int ri = w * 12 + i;
          const int pl = ri & 1;
          const int kbi = (ri >> 1) & 3;
          const int c = (ri >> 3) % 3;
          const int hh = ri / 24;
          const bf16x8 v =
              ld16(&P[(pl * 64 + kbi * 16 + lr) * 200 + hh * 96 + c * 32 + lg * 8]);
          const int hl = b * 32 + hd0 + hh;
          const int kbg = ((s_loc + hf * 64) >> 4) + kbi;
          const long rec3 = ((long)hl * 128 + kbg) * 3 + c;
          *reinterpret_cast<bf16x8*>(dst + (rec3 * 2 + pl) * 512 + lane * 8) = v;
        }
      } else {
        // 48 records: ri = ((hh*6+n)*2+kq)*2+pl; lane holds V^T[n*16+lr][..s..]
#pragma unroll
        for (int i = 0; i < 12; ++i) {
          const int ri = w * 12 + i;
          const int pl = ri & 1;
          const int kq = (ri >> 1) & 1;
          const int n = (ri >> 2) % 6;
          const int hh = ri / 24;
          bf16x8 v;
#pragma unroll
          for (int e = 0; e < 8; ++e)
            v[e] = (short)P[(pl * 64 + kq * 32 + lg * 8 + e) * 200 + hh * 96 + n * 16 + lr];
          const int hl = b * 32 + hd0 + hh;
          const int kqg = ((s_loc + hf * 64) >> 5) + kq;
          const long rec = (((long)hl * 6 + n) * 64 + kqg) * 2 + pl;
          *reinterpret_cast<bf16x8*>(dst + rec * 512 + lane * 8) = v;
        }
      }
    }
  }
}

// ------------------------------------------------------------- attention ---
// r15: 32 q-rows/wave (2 frags), block = 128 q-rows; K/V register loads
// shared across frags. Q from compact Q2 [4096][6144]. Max-free softmax.
__global__ __launch_bounds__(256, 2) void attn_kernel(
    const u16* __restrict__ Q2,
    const u16* __restrict__ Kp, const u16* __restrict__ Vp,
    u16* __restrict__ AO2) {
  __shared__ u16 kv[2][24 * 512];   // 48 KB
  __shared__ u16 pb[4][2][2][512];  // 16 KB: [wave][frag][plane]
  const int lane = threadIdx.x & 63;
  const int wv = threadIdx.x >> 6;
  const int lr = lane & 15, lg = lane >> 4;

  const int nwg = gridDim.x;
  const int bid = blockIdx.x;
  const int wg = (bid & 7) * (nwg >> 3) + (bid >> 3);  // XCD swizzle
  const int hl = wg >> 4;    // b*32 + head
  const int qblk = wg & 15;  // 16 q-blocks of 128 rows
  const int b = hl >> 5;
  const int q0 = qblk * 128 + wv * 32;

  bf16x8 qh[2][3], ql[2][3];
#pragma unroll
  for (int f = 0; f < 2; ++f) {
    const long qofs =
        ((long)(b * 2048 + q0 + f * 16 + lr)) * 6144 + ((hl & 31) * 3) * 64 + lg * 8;
#pragma unroll
    for (int c = 0; c < 3; ++c) {
      qh[f][c] = ld16(Q2 + qofs + c * 64);
      ql[f][c] = ld16(Q2 + qofs + c * 64 + 32);
    }
  }

  f32x4 o_acc[2][6];
#pragma unroll
  for (int f = 0; f < 2; ++f)
#pragma unroll
    for (int n = 0; n < 6; ++n)
#pragma unroll
      for (int j = 0; j < 4; ++j) o_acc[f][n][j] = 0.f;
  float lsum[2][4] = {{0.f, 0.f, 0.f, 0.f}, {0.f, 0.f, 0.f, 0.f}};

  const float scale = 0.10206207261596577f;  // 96^-0.5

  auto stage = [&](int nb, int it) {
    const long kbase = ((long)hl * 768 + (long)it * 12) * 512;
    const long vbase = ((long)hl * 768 + (long)it * 2) * 512;
#pragma unroll
    for (int j = 0; j < 6; ++j) {
      const int r = wv * 6 + j;
      const u16* src;
      if (r < 12) {
        const int tt = r / 6, rc = r % 6;
        src = Kp + kbase + ((long)(tt * 6 + rc)) * 512 + lane * 8;
      } else {
        const int r2 = r - 12;
        src = Vp + vbase + ((long)((r2 >> 1) * 128 + (r2 & 1))) * 512 + lane * 8;
      }
      GLDS16(src, &kv[nb][r * 512]);
    }
  };

  stage(0, 0);
  __syncthreads();

  for (int it = 0; it < 64; ++it) {
    const int nb = it & 1;
    if (it < 63) stage(nb ^ 1, it + 1);
    const u16* L = kv[nb];

    bf16x8 kh0[3], kl0[3], kh1[3], kl1[3];
#pragma unroll
    for (int c = 0; c < 3; ++c) {
      kh0[c] = ld16(L + (c * 2 + 0) * 512 + lane * 8);
      kl0[c] = ld16(L + (c * 2 + 1) * 512 + lane * 8);
      kh1[c] = ld16(L + (6 + c * 2 + 0) * 512 + lane * 8);
      kl1[c] = ld16(L + (6 + c * 2 + 1) * 512 + lane * 8);
    }

    bf16x8 pah[2], pal[2];
#pragma unroll
    for (int f = 0; f < 2; ++f) {
      f32x4 s0, s1;
#pragma unroll
      for (int j = 0; j < 4; ++j) { s0[j] = 0.f; s1[j] = 0.f; }
#pragma unroll
      for (int c = 0; c < 3; ++c) {
        s0 = MFMA(qh[f][c], kh0[c], s0);
        s1 = MFMA(qh[f][c], kh1[c], s1);
        s0 = MFMA(qh[f][c], kl0[c], s0);
        s1 = MFMA(qh[f][c], kl1[c], s1);
        s0 = MFMA(ql[f][c], kh0[c], s0);
        s1 = MFMA(ql[f][c], kh1[c], s1);
      }
      u16* pbh = pb[wv][f][0];
      u16* pbl = pb[wv][f][1];
#pragma unroll
      for (int j = 0; j < 4; ++j) {
        const float p0 = __expf(fmaf(s0[j], scale, -12.f));
        const float p1 = __expf(fmaf(s1[j], scale, -12.f));
        lsum[f][j] += p0 + p1;
        const int r = lg * 4 + j;
        const int key = j ^ lg;
        u16 h, l;
        split2(p0, h, l);
        const int a0 = r * 32 + ((((lr >> 3) ^ key) & 3) << 3) + (lr & 7);
        pbh[a0] = h;
        pbl[a0] = l;
        split2(p1, h, l);
        const int a1 = r * 32 + ((((2 + (lr >> 3)) ^ key) & 3) << 3) + (lr & 7);
        pbh[a1] = h;
        pbl[a1] = l;
      }
      const int rkey = (lr & 3) ^ (lr >> 2);
      const int ra = lr * 32 + (((lg ^ rkey) & 3) << 3);
      pah[f] = ld16(&pbh[ra]);
      pal[f] = ld16(&pbl[ra]);
    }

#pragma unroll
    for (int n = 0; n < 6; ++n) {
      const bf16x8 vh = ld16(L + (12 + n * 2 + 0) * 512 + lane * 8);
      const bf16x8 vl = ld16(L + (12 + n * 2 + 1) * 512 + lane * 8);
#pragma unroll
      for (int f = 0; f < 2; ++f) {
        o_acc[f][n] = MFMA(pah[f], vh, o_acc[f][n]);
        o_acc[f][n] = MFMA(pah[f], vl, o_acc[f][n]);
        o_acc[f][n] = MFMA(pal[f], vh, o_acc[f][n]);
      }
    }
    __syncthreads();
  }

#pragma unroll
  for (int f = 0; f < 2; ++f) {
    float inv[4];
#pragma unroll
    for (int j = 0; j < 4; ++j) {
      float rs = lsum[f][j];
#pragma unroll
      for (int mk = 1; mk < 16; mk <<= 1) rs += __shfl_xor(rs, mk);
      inv[j] = 1.f / rs;
    }
#pragma unroll
    for (int n = 0; n < 6; ++n)
#pragma unroll
      for (int j = 0; j < 4; ++j) {
        const long row = (long)(b * 2048 + q0 + f * 16 + lg * 4 + j);
        const long idx =
            row * 6144 + ((hl & 31) * 3 + (n >> 1)) * 64 + (n & 1) * 16 + lr;
        u16 h, l;
        split2(o_acc[f][n][j] * inv[j], h, l);
        AO2[idx] = h;
        AO2[idx + 32] = l;
      }
  }
}

// ---------------------------------------------------------------- launch ---
extern "C" void kernel_launch(void* const* d_in, const int* in_sizes, int n_in,
                              void* d_out, int out_size, void* d_ws, size_t ws_size,
                              hipStream_t stream) {
  const float* x = (const float*)d_in[0];     // [4096][3072]
  const float* wqkv = (const float*)d_in[1];  // [9216][3072]
  const float* wo = (const float*)d_in[2];    // [3072][3072]
  const float* bo = (const float*)d_in[3];    // [3072]
  float* out = (float*)d_out;                 // [4096][3072]
  char* ws = (char*)d_ws;

  const size_t E_X = (size_t)4096 * 3072;
  const size_t E_WQ = (size_t)9216 * 3072;
  const size_t E_WO = (size_t)3072 * 3072;

  // layout (bytes): X2[4E_X] | W2[4E_WQ] | Q2[4E_X] | KP[4E_X] | VP[4E_X]
  // after GEMM1, W2 region is dead -> AO2 (4E_X) + WO2 (4E_WO) fit inside.
  u16* X2 = (u16*)ws;
  char* W0 = ws + 4 * E_X;
  u16* W2 = (u16*)W0;
  u16* Q2 = (u16*)(W0 + 4 * E_WQ);
  u16* KP = Q2 + 2 * E_X;  // (4E_X bytes each region = 2*E_X u16)
  u16* VP = KP + 2 * E_X;
  u16* AO2 = (u16*)W0;
  u16* WO2 = (u16*)(W0 + 4 * E_X);

  const size_t need = 4 * (4 * E_X + E_WQ);  // 314.6 MB
  if (ws_size < need) return;

  split_kernel<<<12288, 256, 0, stream>>>(x, X2, (long)E_X);
  split_kernel<<<27648, 256, 0, stream>>>(wqkv, W2, (long)E_WQ);
  gemm32<2><<<1536, 256, 0, stream>>>(X2, W2, 4096, 9216, Q2, KP, VP,
                                      nullptr, nullptr);
  split_kernel<<<9216, 256, 0, stream>>>(wo, WO2, (long)E_WO);
  attn_kernel<<<1024, 256, 0, stream>>>(Q2, KP, VP, AO2);
  gemm32<1><<<512, 256, 0, stream>>>(AO2, WO2, 4096, 3072, nullptr, nullptr,
                                     nullptr, out, bo);
}